// Round 4
// baseline (187.205 us; speedup 1.0000x reference)
//
#include <hip/hip_runtime.h>
#include <math.h>

#define C 8
#define K 128
#define S 64
#define L 2048
#define NB 64
#define W (L - S + 1)   // 1985
#define TW 128
#define NTW 16
#define XCS 200         // padded stride of shifted x copies (400 B, 16B-aligned)
#define XFS 200         // fp32 x scratch stride (192 data + 8 zero pad)

typedef __attribute__((ext_vector_type(8))) short bf16x8;
typedef __attribute__((ext_vector_type(4))) float f32x4;

__device__ __forceinline__ unsigned short f2bf(float f) {
  unsigned int u = __float_as_uint(f);
  u += 0x7FFFu + ((u >> 16) & 1u);   // RNE
  return (unsigned short)(u >> 16);
}

// prep: z-normalize shapelets -> bf16 * (-2) in exact B-fragment order;
// sum(z^2) fp32; init out to +inf (harness re-poisons d_out every call).
__global__ __launch_bounds__(256) void prep_kernel(const float* __restrict__ sh,
                                                   unsigned short* __restrict__ shzB,
                                                   float* __restrict__ sqs,
                                                   float* __restrict__ out) {
  int tid = blockIdx.x * 256 + threadIdx.x;
  if (tid < NB * K) out[tid] = __int_as_float(0x7F800000);
  int gid = blockIdx.x * 4 + (threadIdx.x >> 6);  // c*K + k
  int lane = threadIdx.x & 63;                    // = s
  float v = sh[(size_t)gid * S + lane];
  float s1 = v, s2 = v * v;
#pragma unroll
  for (int off = 32; off > 0; off >>= 1) {
    s1 += __shfl_down(s1, off);
    s2 += __shfl_down(s2, off);
  }
  s1 = __shfl(s1, 0);
  s2 = __shfl(s2, 0);
  float mu = s1 * (1.0f / S);
  float sd = sqrtf(fmaxf(s2 * (1.0f / S) - mu * mu, 0.0f));
  float z = (v - mu) / sd;
  int c = gid >> 7, k = gid & (K - 1), s = lane;
  // B-frag layout: [c][k>>4][s>>5][lane' = ((s>>3)&3)*16 + (k&15)][s&7]
  int idx = c * 8192 + ((k >> 4) * 2 + (s >> 5)) * 512 +
            ((((s >> 3) & 3) * 16 + (k & 15)) * 8) + (s & 7);
  shzB[idx] = f2bf(-2.0f * z);   // bake the -2 of d2 = sqx + sqs - 2*cross
  float z2 = z * z;
#pragma unroll
  for (int off = 32; off > 0; off >>= 1) z2 += __shfl_down(z2, off);
  if (lane == 0) sqs[gid] = z2;
}

// main: block = 128w x 128k, 512 threads = 8 waves, each wave 64w x 32k.
// B fragments come straight from global (L2) into VGPRs -> no per-channel
// barriers; channel loop fully unrolled & software-pipelined by compiler.
__global__ __launch_bounds__(512, 4) void main_kernel(const float* __restrict__ x,
                                                      const unsigned short* __restrict__ shzB,
                                                      const float* __restrict__ sqs,
                                                      int* __restrict__ out) {
  __shared__ __align__(16) unsigned short xcop[C][8][XCS]; // 8 shifted bf16 copies, 25.6 KB
  __shared__ __align__(16) float sqx[C][TW];               // 4 KB
  __shared__ __align__(16) float xf[C][XFS];               // 6.4 KB fp32 staging
  __shared__ __align__(16) float sqsl[C * K];              // 4 KB

  const int t = threadIdx.x;
  const int lane = t & 63;
  const int wave = t >> 6;     // 0..7
  const int wgrp = wave & 1;   // w-offset 64
  const int kgrp = wave >> 1;  // k-offset 32 (0..3)
  const int col = lane & 15;
  const int quad = lane >> 4;
  const int n = blockIdx.y;
  const int w0 = blockIdx.x * TW;
  const float* xn = x + (size_t)n * C * L;

  // ---- stage fp32 x segment (8 ch x 192, stride 200, zero-padded) ----
#pragma unroll
  for (int j = 0; j < 4; ++j) {
    int s = j * 512 + t;
    if (s < C * XFS) {
      int c = s / XFS, e = s - c * XFS;
      int g = w0 + e;
      ((float*)xf)[s] = (e < 192 && g < L) ? xn[c * L + g] : 0.0f;
    }
  }
  // ---- stage sqs -> LDS (read every channel iter; keep latency off epilogue) ----
  sqsl[t] = sqs[t];
  sqsl[t + 512] = sqs[t + 512];
  __syncthreads();

  // ---- build 8 shifted bf16 copies: wave r builds copy r for all channels ----
  {
    const int q = lane, r = wave;
#pragma unroll
    for (int c = 0; c < C; ++c) {
      {
        int i = q * 2;  // 0..126
        unsigned int pk = (unsigned int)f2bf(xf[c][i + r]) |
                          ((unsigned int)f2bf(xf[c][i + r + 1]) << 16);
        *(unsigned int*)&xcop[c][r][i] = pk;
      }
      if (q < 32) {
        int i = 128 + q * 2;  // 128..190
        unsigned int pk = (unsigned int)f2bf(xf[c][i + r]) |
                          ((unsigned int)f2bf(xf[c][i + r + 1]) << 16);
        *(unsigned int*)&xcop[c][r][i] = pk;
      }
    }
  }
  // ---- sliding-window fp32 sqx: thread -> (c, 2 consecutive w) ----
  {
    int c = t >> 6, wl = (t & 63) * 2;
    const float* xr = xf[c];
    float s0 = 0.0f;
#pragma unroll
    for (int si = 0; si < S; ++si) { float v = xr[wl + si]; s0 = fmaf(v, v, s0); }
    sqx[c][wl] = s0;
    float a = xr[wl + S], b = xr[wl];
    sqx[c][wl + 1] = s0 + a * a - b * b;
  }
  __syncthreads();  // xcop/sqx/sqsl ready; NO more barriers from here on

  const f32x4 z4 = {0.0f, 0.0f, 0.0f, 0.0f};
  f32x4 dsum[4][2];
#pragma unroll
  for (int a = 0; a < 4; ++a)
#pragma unroll
    for (int b = 0; b < 2; ++b) dsum[a][b] = z4;

  const int r = col & 7;
  const int abase = wgrp * 64 + (col - r) + quad * 8;  // multiple of 8 -> b128 aligned
  const unsigned short* bglob = shzB + (size_t)lane * 8;

#pragma unroll
  for (int c = 0; c < C; ++c) {
    // B fragments: global -> VGPR (coalesced 1KB/instr, L2-resident, vmcnt-pipelined)
    bf16x8 bfr[2][2];
#pragma unroll
    for (int ks = 0; ks < 2; ++ks)
#pragma unroll
      for (int kt = 0; kt < 2; ++kt)
        bfr[ks][kt] = *(const bf16x8*)(bglob + c * 8192 + ((kgrp * 2 + kt) * 2 + ks) * 512);

    // acc init = sqx + sqs  (d2 falls directly out of the MFMA chain)
    f32x4 acc[4][2];
    float sq0 = sqsl[c * K + kgrp * 32 + col];
    float sq1 = sqsl[c * K + kgrp * 32 + 16 + col];
#pragma unroll
    for (int wt = 0; wt < 4; ++wt) {
      f32x4 sx = *(const f32x4*)&sqx[c][wgrp * 64 + wt * 16 + quad * 4];
#pragma unroll
      for (int i = 0; i < 4; ++i) {
        acc[wt][0][i] = sx[i] + sq0;
        acc[wt][1][i] = sx[i] + sq1;
      }
    }

#pragma unroll
    for (int ks = 0; ks < 2; ++ks) {
      bf16x8 afr[4];
#pragma unroll
      for (int wt = 0; wt < 4; ++wt)
        afr[wt] = *(const bf16x8*)(&xcop[c][r][0] + abase + wt * 16 + ks * 32);
#pragma unroll
      for (int wt = 0; wt < 4; ++wt) {
        acc[wt][0] = __builtin_amdgcn_mfma_f32_16x16x32_bf16(afr[wt], bfr[ks][0], acc[wt][0], 0, 0, 0);
        acc[wt][1] = __builtin_amdgcn_mfma_f32_16x16x32_bf16(afr[wt], bfr[ks][1], acc[wt][1], 0, 0, 0);
      }
    }

    // epilogue: dsum += v_sqrt(max(d2, eps))
#pragma unroll
    for (int wt = 0; wt < 4; ++wt)
#pragma unroll
      for (int kt = 0; kt < 2; ++kt)
#pragma unroll
        for (int i = 0; i < 4; ++i)
          dsum[wt][kt][i] += __builtin_amdgcn_sqrtf(fmaxf(acc[wt][kt][i], 1e-12f));
  }

  // min over w (regs -> quad shuffles), one atomicMin per k
  const float INF = __int_as_float(0x7F800000);
  int wbase = w0 + wgrp * 64;
#pragma unroll
  for (int kt = 0; kt < 2; ++kt) {
    float mv = INF;
#pragma unroll
    for (int wt = 0; wt < 4; ++wt)
#pragma unroll
      for (int i = 0; i < 4; ++i) {
        int w = wbase + wt * 16 + quad * 4 + i;
        mv = (w < W) ? fminf(mv, dsum[wt][kt][i]) : mv;
      }
    mv = fminf(mv, __shfl_xor(mv, 16));
    mv = fminf(mv, __shfl_xor(mv, 32));
    if (quad == 0)
      atomicMin(&out[n * K + kgrp * 32 + kt * 16 + col], __float_as_int(mv));
  }
}

extern "C" void kernel_launch(void* const* d_in, const int* in_sizes, int n_in,
                              void* d_out, int out_size, void* d_ws, size_t ws_size,
                              hipStream_t stream) {
  const float* x = (const float*)d_in[0];    // (64, 8, 2048) fp32
  const float* sh = (const float*)d_in[1];   // (8, 128, 64) fp32
  float* out = (float*)d_out;                // (64, 1, 128) fp32
  unsigned short* shzB = (unsigned short*)d_ws;             // 128 KB bf16 B-frag layout (scaled -2)
  float* sqs = (float*)((char*)d_ws + C * K * S * 2);       // 4 KB fp32

  prep_kernel<<<256, 256, 0, stream>>>(sh, shzB, sqs, out);
  main_kernel<<<dim3(NTW, NB), 512, 0, stream>>>(x, shzB, sqs, (int*)out);
}

// Round 5
// 96.558 us; speedup vs baseline: 1.9388x; 1.9388x over previous
//
#include <hip/hip_runtime.h>
#include <math.h>

#define C 8
#define K 128
#define S 64
#define L 2048
#define NB 64
#define W (L - S + 1)   // 1985
#define TW 128
#define NTW 16
#define XCS 200         // stride (shorts) of each shifted bf16 copy
#define XFS 200         // fp32 x scratch stride (192 data + 8 zero pad)

typedef __attribute__((ext_vector_type(8))) short bf16x8;
typedef __attribute__((ext_vector_type(4))) short short4v;
typedef __attribute__((ext_vector_type(4))) float f32x4;

__device__ __forceinline__ unsigned short f2bf(float f) {
  unsigned int u = __float_as_uint(f);
  u += 0x7FFFu + ((u >> 16) & 1u);   // RNE
  return (unsigned short)(u >> 16);
}

// prep: z-normalize shapelets -> bf16 * (-2) in exact B-fragment order;
// sum(z^2) fp32; init out to +inf (harness re-poisons d_out every call).
__global__ __launch_bounds__(256) void prep_kernel(const float* __restrict__ sh,
                                                   unsigned short* __restrict__ shzB,
                                                   float* __restrict__ sqs,
                                                   float* __restrict__ out) {
  int tid = blockIdx.x * 256 + threadIdx.x;
  if (tid < NB * K) out[tid] = __int_as_float(0x7F800000);
  int gid = blockIdx.x * 4 + (threadIdx.x >> 6);  // c*K + k
  int lane = threadIdx.x & 63;                    // = s
  float v = sh[(size_t)gid * S + lane];
  float s1 = v, s2 = v * v;
#pragma unroll
  for (int off = 32; off > 0; off >>= 1) {
    s1 += __shfl_down(s1, off);
    s2 += __shfl_down(s2, off);
  }
  s1 = __shfl(s1, 0);
  s2 = __shfl(s2, 0);
  float mu = s1 * (1.0f / S);
  float sd = sqrtf(fmaxf(s2 * (1.0f / S) - mu * mu, 0.0f));
  float z = (v - mu) / sd;
  int c = gid >> 7, k = gid & (K - 1), s = lane;
  // B-frag layout: [c][k>>4][s>>5][lane' = ((s>>3)&3)*16 + (k&15)][s&7]
  int idx = c * 8192 + ((k >> 4) * 2 + (s >> 5)) * 512 +
            ((((s >> 3) & 3) * 16 + (k & 15)) * 8) + (s & 7);
  shzB[idx] = f2bf(-2.0f * z);   // bake the -2 of d2 = sqx + sqs - 2*cross
  float z2 = z * z;
#pragma unroll
  for (int off = 32; off > 0; off >>= 1) z2 += __shfl_down(z2, off);
  if (lane == 0) sqs[gid] = z2;
}

// main: block = 128w x 128k, 512 threads = 8 waves, wave tile 64w x 32k.
// B double-buffered in LDS via global_load_lds (keeps HBM ~0 — R4 showed
// per-wave global B reads go to memory, 183MB fetched). 53.8KB LDS +
// launch_bounds(512,4) -> 16 waves/CU.
__global__ __launch_bounds__(512, 4) void main_kernel(const float* __restrict__ x,
                                                      const unsigned short* __restrict__ shzB,
                                                      const float* __restrict__ sqs,
                                                      int* __restrict__ out) {
  __shared__ __align__(16) unsigned short bbuf[2][8192];   // B dbuf, 16 KB each
  __shared__ __align__(16) unsigned short xcop[C][4][XCS]; // 4 shifted bf16 copies, 12.8 KB
  __shared__ __align__(16) float sqx[C][TW];               // 4 KB
  __shared__ __align__(16) float sqsl[C * K];              // 4 KB

  const int t = threadIdx.x;
  const int lane = t & 63;
  const int wave = t >> 6;     // 0..7
  const int wgrp = wave & 1;   // w-offset 64
  const int kgrp = wave >> 1;  // k-offset 32 (0..3)
  const int col = lane & 15;
  const int quad = lane >> 4;
  const int n = blockIdx.y;
  const int w0 = blockIdx.x * TW;
  const float* xn = x + (size_t)n * C * L;

  // ---- async stage B channel 0 into bbuf[0] ----
  {
    const unsigned short* g = shzB + t * 8;
    unsigned short* lb = &bbuf[0][wave * 512];
#pragma unroll
    for (int i = 0; i < 2; ++i)
      __builtin_amdgcn_global_load_lds(
          (const __attribute__((address_space(1))) void*)(g + i * 4096),
          (__attribute__((address_space(3))) void*)(lb + i * 4096), 16, 0, 0);
  }

  // ---- stage fp32 x segment (8 ch x 192, stride 200, zero-padded) into bbuf[1] ----
  float* xf = (float*)&bbuf[1][0];  // 1600 floats, fits in 16 KB scratch
#pragma unroll
  for (int j = 0; j < 4; ++j) {
    int s = j * 512 + t;
    if (s < C * XFS) {
      int c = s / XFS, e = s - c * XFS;
      int g = w0 + e;
      xf[s] = (e < 192 && g < L) ? xn[c * L + g] : 0.0f;
    }
  }
  // ---- sqs -> LDS ----
  sqsl[t] = sqs[t];
  sqsl[t + 512] = sqs[t + 512];
  __syncthreads();

  // ---- build 4 shifted bf16 copies: copy_r[i] = xseg[i+r], r=0..3 ----
  // flat: 8c x 4r x 96 dwords = 3072 dwords over 512 threads
#pragma unroll
  for (int j = 0; j < 6; ++j) {
    int idx = j * 512 + t;
    int c = idx / 384, rem = idx - c * 384;
    int r = rem / 96, i2 = rem - r * 96;
    int i = i2 * 2;
    unsigned int pk = (unsigned int)f2bf(xf[c * XFS + i + r]) |
                      ((unsigned int)f2bf(xf[c * XFS + i + r + 1]) << 16);
    *(unsigned int*)&xcop[c][r][i] = pk;
  }
  // ---- sliding-window fp32 sqx: wave c, lane -> 2 consecutive w ----
  {
    int c = wave, wl = lane * 2;
    const float* xr = xf + c * XFS;
    float s0 = 0.0f;
#pragma unroll
    for (int si = 0; si < S; ++si) { float v = xr[wl + si]; s0 = fmaf(v, v, s0); }
    sqx[c][wl] = s0;
    float a = xr[wl + S], b = xr[wl];
    sqx[c][wl + 1] = s0 + a * a - b * b;
  }
  __syncthreads();  // xf dead; bbuf[1] free as prefetch target

  const f32x4 z4 = {0.0f, 0.0f, 0.0f, 0.0f};
  f32x4 dsum[4][2];
#pragma unroll
  for (int a = 0; a < 4; ++a)
#pragma unroll
    for (int b = 0; b < 2; ++b) dsum[a][b] = z4;

  const int r4 = col & 3;
  const int abase = wgrp * 64 + (col - r4) + quad * 8;  // multiple of 4 -> b64 aligned

  for (int c = 0; c < C; ++c) {
    // prefetch next channel's B into the other buffer
    if (c + 1 < C) {
      const unsigned short* g = shzB + (c + 1) * 8192 + t * 8;
      unsigned short* lb = &bbuf[(c + 1) & 1][wave * 512];
#pragma unroll
      for (int i = 0; i < 2; ++i)
        __builtin_amdgcn_global_load_lds(
            (const __attribute__((address_space(1))) void*)(g + i * 4096),
            (__attribute__((address_space(3))) void*)(lb + i * 4096), 16, 0, 0);
    }
    const unsigned short* bb = bbuf[c & 1];
    const unsigned short* xc = &xcop[c][r4][0];

    // B fragments from LDS (b128, 16B aligned)
    bf16x8 bfr[2][2];
#pragma unroll
    for (int ks = 0; ks < 2; ++ks)
#pragma unroll
      for (int kt = 0; kt < 2; ++kt)
        bfr[ks][kt] = *(const bf16x8*)(bb + ((kgrp * 2 + kt) * 2 + ks) * 512 + lane * 8);

    // acc init = sqx + sqs  (d2 falls directly out of the MFMA chain)
    f32x4 acc[4][2];
    float sq0 = sqsl[c * K + kgrp * 32 + col];
    float sq1 = sqsl[c * K + kgrp * 32 + 16 + col];
#pragma unroll
    for (int wt = 0; wt < 4; ++wt) {
      f32x4 sx = *(const f32x4*)&sqx[c][wgrp * 64 + wt * 16 + quad * 4];
#pragma unroll
      for (int i = 0; i < 4; ++i) {
        acc[wt][0][i] = sx[i] + sq0;
        acc[wt][1][i] = sx[i] + sq1;
      }
    }

#pragma unroll
    for (int ks = 0; ks < 2; ++ks) {
      bf16x8 afr[4];
#pragma unroll
      for (int wt = 0; wt < 4; ++wt) {
        int b = abase + wt * 16 + ks * 32;  // element index, mult of 4 -> 8B aligned
        short4v lo = *(const short4v*)(xc + b);
        short4v hi = *(const short4v*)(xc + b + 4);
        afr[wt] = __builtin_shufflevector(lo, hi, 0, 1, 2, 3, 4, 5, 6, 7);
      }
#pragma unroll
      for (int wt = 0; wt < 4; ++wt) {
        acc[wt][0] = __builtin_amdgcn_mfma_f32_16x16x32_bf16(afr[wt], bfr[ks][0], acc[wt][0], 0, 0, 0);
        acc[wt][1] = __builtin_amdgcn_mfma_f32_16x16x32_bf16(afr[wt], bfr[ks][1], acc[wt][1], 0, 0, 0);
      }
    }

    // epilogue: dsum += v_sqrt(max(d2, eps))
#pragma unroll
    for (int wt = 0; wt < 4; ++wt)
#pragma unroll
      for (int kt = 0; kt < 2; ++kt)
#pragma unroll
        for (int i = 0; i < 4; ++i)
          dsum[wt][kt][i] += __builtin_amdgcn_sqrtf(fmaxf(acc[wt][kt][i], 1e-12f));

    __syncthreads();  // prefetch landed + all waves done with bb
  }

  // min over w (regs -> quad shuffles), one atomicMin per k
  const float INF = __int_as_float(0x7F800000);
  int wbase = w0 + wgrp * 64;
#pragma unroll
  for (int kt = 0; kt < 2; ++kt) {
    float mv = INF;
#pragma unroll
    for (int wt = 0; wt < 4; ++wt)
#pragma unroll
      for (int i = 0; i < 4; ++i) {
        int w = wbase + wt * 16 + quad * 4 + i;
        mv = (w < W) ? fminf(mv, dsum[wt][kt][i]) : mv;
      }
    mv = fminf(mv, __shfl_xor(mv, 16));
    mv = fminf(mv, __shfl_xor(mv, 32));
    if (quad == 0)
      atomicMin(&out[n * K + kgrp * 32 + kt * 16 + col], __float_as_int(mv));
  }
}

extern "C" void kernel_launch(void* const* d_in, const int* in_sizes, int n_in,
                              void* d_out, int out_size, void* d_ws, size_t ws_size,
                              hipStream_t stream) {
  const float* x = (const float*)d_in[0];    // (64, 8, 2048) fp32
  const float* sh = (const float*)d_in[1];   // (8, 128, 64) fp32
  float* out = (float*)d_out;                // (64, 1, 128) fp32
  unsigned short* shzB = (unsigned short*)d_ws;             // 128 KB bf16 B-frag layout (scaled -2)
  float* sqs = (float*)((char*)d_ws + C * K * S * 2);       // 4 KB fp32

  prep_kernel<<<256, 256, 0, stream>>>(sh, shzB, sqs, out);
  main_kernel<<<dim3(NTW, NB), 512, 0, stream>>>(x, shzB, sqs, (int*)out);
}